// Round 15
// baseline (70.385 us; speedup 1.0000x reference)
//
#include <hip/hip_runtime.h>
#include <math.h>

// Directional Chamfer: sum_m min_n ||t_m - s_n||^2.  SINGLE dispatch.
// q = 2 t.s - |s|^2 (maximize), d2 = |t|^2 - qmax.
// Grid (10,100): each block sweeps 1024 templates x 200 LDS-staged scan pts
// (v_pk_fma_f32 + v_max3_f32, TPT=4), then ONE relaxed fire-and-forget
// atomicMax per owned template into module-scope g_qmax (order-preserving
// uint map -> bit-exact float max at the device coherence point).
// Last-block ticket (fully RELAXED — no fences, R9 lesson): each block's
// atomicMax ops are vmcnt-drained by __syncthreads before its ticket add,
// so ticket==nblk-1 implies every max has completed at the coherence point.
// Winner reads g_qmax via relaxed atomic loads, RE-ZEROES it (self-restoring
// invariant for graph replays; g_qmax/.bss is zero at module load), computes
// d2 + fixed-order sum -> out. Bit-deterministic regardless of winner.

typedef float v2 __attribute__((ext_vector_type(2)));

#define TPT 4
#define BLK 256
#define MPB (TPT * BLK)   // 1024 templates per block-stripe
#define CHUNK 200         // scan points per chunk (100*200 = 20000 exactly)
#define QCAP 16384

__device__ unsigned g_qmax[QCAP];  // .bss -> zero at module load
__device__ unsigned g_done;        // ticket; winner self-restores to 0

__device__ __forceinline__ v2 pk_fma(v2 a, v2 b, v2 c) {
    v2 d;
    asm("v_pk_fma_f32 %0, %1, %2, %3" : "=v"(d) : "v"(a), "v"(b), "v"(c));
    return d;
}
__device__ __forceinline__ float max3(float a, float b, float c) {
    float d;
    asm("v_max3_f32 %0, %1, %2, %3" : "=v"(d) : "v"(a), "v"(b), "v"(c));
    return d;
}

// Order-preserving map float -> uint32 (monotone; map(f) > 0 for all f,
// so 0 is a safe identity for unsigned max).
__device__ __forceinline__ unsigned map_f32(float f) {
    unsigned b = __float_as_uint(f);
    return (b & 0x80000000u) ? ~b : (b | 0x80000000u);
}
__device__ __forceinline__ float unmap_f32(unsigned u) {
    unsigned b = (u & 0x80000000u) ? (u ^ 0x80000000u) : ~u;
    return __uint_as_float(b);
}

__global__ void __launch_bounds__(BLK) chamfer_fused(
    const float* __restrict__ scan, const float* __restrict__ tmpl,
    float* __restrict__ out, int M, int N, int nblk) {
    __shared__ float4 lds4[CHUNK];  // 2 float4 per pair
    float* ldsf = (float*)lds4;

    int c = blockIdx.y;
    int j0 = c * CHUNK;
    int cnt = N - j0;
    if (cnt > CHUNK) cnt = CHUNK;

    for (int i = threadIdx.x; i < cnt; i += BLK) {
        float x = scan[3 * (j0 + i) + 0];
        float y = scan[3 * (j0 + i) + 1];
        float z = scan[3 * (j0 + i) + 2];
        float* bp = &ldsf[(i >> 1) * 8];
        int h = i & 1;
        bp[0 + h] = 2.f * x;
        bp[2 + h] = 2.f * y;
        bp[4 + h] = 2.f * z;
        bp[6 + h] = -(x * x + y * y + z * z);
    }
    if ((cnt & 1) && threadIdx.x == 0) {  // pad odd tail so hi half is inert
        float* bp = &ldsf[(cnt >> 1) * 8];
        bp[1] = 0.f; bp[3] = 0.f; bp[5] = 0.f; bp[7] = -INFINITY;
    }
    __syncthreads();

    int base = blockIdx.x * MPB + threadIdx.x;
    v2 txx[TPT], tyy[TPT], tzz[TPT];
    float q[TPT];
#pragma unroll
    for (int k = 0; k < TPT; ++k) {
        int m = base + k * BLK;
        float x = 0.f, y = 0.f, z = 0.f;
        if (m < M) {
            x = tmpl[3 * m + 0];
            y = tmpl[3 * m + 1];
            z = tmpl[3 * m + 2];
        }
        txx[k] = (v2){x, x};
        tyy[k] = (v2){y, y};
        tzz[k] = (v2){z, z};
        q[k] = -INFINITY;
    }

    int npair = (cnt + 1) >> 1;
#pragma unroll 4
    for (int p = 0; p < npair; ++p) {
        float4 a = lds4[2 * p + 0];  // broadcast: {2x0,2x1,2y0,2y1}
        float4 b = lds4[2 * p + 1];  // {2z0,2z1,-n0,-n1}
        v2 xx = (v2){a.x, a.y};
        v2 yy = (v2){a.z, a.w};
        v2 zz = (v2){b.x, b.y};
        v2 ww = (v2){b.z, b.w};
#pragma unroll
        for (int k = 0; k < TPT; ++k) {
            v2 r = pk_fma(tzz[k], zz, ww);
            r = pk_fma(tyy[k], yy, r);
            r = pk_fma(txx[k], xx, r);
            q[k] = max3(q[k], r.x, r.y);
        }
    }

    // One relaxed fire-and-forget atomic per owned template point.
#pragma unroll
    for (int k = 0; k < TPT; ++k) {
        int m = base + k * BLK;
        if (m < M) atomicMax(&g_qmax[m], map_f32(q[k]));
    }

    // ---- last-block ticket (fully relaxed) ----
    __syncthreads();  // s_barrier drain: our atomicMax ops completed at L2
    __shared__ int slast;
    if (threadIdx.x == 0) {
        unsigned t = __hip_atomic_fetch_add(&g_done, 1u, __ATOMIC_RELAXED,
                                            __HIP_MEMORY_SCOPE_AGENT);
        int l = (t == (unsigned)(nblk - 1));
        if (l)  // self-restore for next call/replay
            __hip_atomic_store(&g_done, 0u, __ATOMIC_RELAXED,
                               __HIP_MEMORY_SCOPE_AGENT);
        slast = l;
    }
    __syncthreads();
    if (!slast) return;

    // ---- winner: d2 + fixed-order sum + g_qmax self-restore ----
    float acc = 0.f;
    for (int m = threadIdx.x; m < M; m += BLK) {
        unsigned u = __hip_atomic_load(&g_qmax[m], __ATOMIC_RELAXED,
                                       __HIP_MEMORY_SCOPE_AGENT);
        __hip_atomic_store(&g_qmax[m], 0u, __ATOMIC_RELAXED,
                           __HIP_MEMORY_SCOPE_AGENT);
        float qmax = unmap_f32(u);
        float x = tmpl[3 * m + 0];
        float y = tmpl[3 * m + 1];
        float z = tmpl[3 * m + 2];
        float d2 = fmaf(x, x, fmaf(y, y, z * z)) - qmax;
        if (d2 < 0.f) d2 = 0.f;
        acc += d2;
    }
    for (int off = 32; off >= 1; off >>= 1) acc += __shfl_down(acc, off, 64);
    __shared__ float wsum[4];
    int lane = threadIdx.x & 63;
    int wid = threadIdx.x >> 6;
    if (lane == 0) wsum[wid] = acc;
    __syncthreads();
    if (threadIdx.x == 0)
        out[0] = wsum[0] + wsum[1] + wsum[2] + wsum[3];
}

extern "C" void kernel_launch(void* const* d_in, const int* in_sizes, int n_in,
                              void* d_out, int out_size, void* d_ws,
                              size_t ws_size, hipStream_t stream) {
    const float* scan = (const float*)d_in[0];   // [N,3]
    const float* tmpl = (const float*)d_in[1];   // [M,3]
    int N = in_sizes[0] / 3;
    int M = in_sizes[1] / 3;
    float* out = (float*)d_out;

    int GX = (M + MPB - 1) / MPB;        // 10
    int NC = (N + CHUNK - 1) / CHUNK;    // 100
    int nblk = GX * NC;                  // 1000

    dim3 grid(GX, NC);
    chamfer_fused<<<grid, BLK, 0, stream>>>(scan, tmpl, out, M, N, nblk);
}

// Round 16
// 30.993 us; speedup vs baseline: 2.2710x; 2.2710x over previous
//
#include <hip/hip_runtime.h>
#include <math.h>

// Directional Chamfer: sum_m min_n ||t_m - s_n||^2.
// q = 2 t.s - |s|^2 (maximize), d2 = |t|^2 - qmax.
// 2 dispatches (R15 lesson: NEVER barrier-wait in-kernel on contended
// device atomics — fire-and-forget + kernel-boundary drain is cheap):
//   1) main grid (10,50): LDS pair-packed chunk of 400 scan pts,
//      v_pk_fma_f32 + v_max3_f32, TPT=4; per-thread register max over the
//      chunk, then ONE relaxed fire-and-forget atomicMax per owned template
//      into module-scope g_qmax (order-preserving uint map -> bit-exact max;
//      relaxed = no fence = no cross-XCD L2 thrash, R9 lesson).
//      CHUNK=400 halves atomic count & per-address contention vs R14.
//   2) final grid 40: one coalesced load per template, d2, fixed-order block
//      sum; each block RE-ZEROES its own g_qmax slice (sole reader; stream
//      order publishes zeros before next replay's main) -> self-restoring
//      invariant, so every call starts from g_qmax == 0 (.bss at load).
//      Last-block ticket does the fixed-order final sum -> out.
// All maxes order-independent, all sums fixed-order -> bit-deterministic.

typedef float v2 __attribute__((ext_vector_type(2)));

#define TPT 4
#define BLK 256
#define MPB (TPT * BLK)   // 1024 templates per block-stripe
#define CHUNK 400         // scan points per chunk (50*400 = 20000 exactly)
#define QCAP 16384

__device__ unsigned g_qmax[QCAP];  // .bss -> zero at module load
__device__ unsigned g_done;        // ticket; winner self-restores to 0

__device__ __forceinline__ v2 pk_fma(v2 a, v2 b, v2 c) {
    v2 d;
    asm("v_pk_fma_f32 %0, %1, %2, %3" : "=v"(d) : "v"(a), "v"(b), "v"(c));
    return d;
}
__device__ __forceinline__ float max3(float a, float b, float c) {
    float d;
    asm("v_max3_f32 %0, %1, %2, %3" : "=v"(d) : "v"(a), "v"(b), "v"(c));
    return d;
}

// Order-preserving map float -> uint32 (monotone: a<b <=> map(a)<map(b));
// map(f) > 0 for every float f, so 0 is a safe identity for max.
__device__ __forceinline__ unsigned map_f32(float f) {
    unsigned b = __float_as_uint(f);
    return (b & 0x80000000u) ? ~b : (b | 0x80000000u);
}
__device__ __forceinline__ float unmap_f32(unsigned u) {
    unsigned b = (u & 0x80000000u) ? (u ^ 0x80000000u) : ~u;
    return __uint_as_float(b);
}

__global__ void __launch_bounds__(BLK) chamfer_main(
    const float* __restrict__ scan, const float* __restrict__ tmpl, int M,
    int N) {
    __shared__ float4 lds4[CHUNK];  // 2 float4 per pair
    float* ldsf = (float*)lds4;

    int c = blockIdx.y;
    int j0 = c * CHUNK;
    int cnt = N - j0;
    if (cnt > CHUNK) cnt = CHUNK;

    for (int i = threadIdx.x; i < cnt; i += BLK) {
        float x = scan[3 * (j0 + i) + 0];
        float y = scan[3 * (j0 + i) + 1];
        float z = scan[3 * (j0 + i) + 2];
        float* bp = &ldsf[(i >> 1) * 8];
        int h = i & 1;
        bp[0 + h] = 2.f * x;
        bp[2 + h] = 2.f * y;
        bp[4 + h] = 2.f * z;
        bp[6 + h] = -(x * x + y * y + z * z);
    }
    if ((cnt & 1) && threadIdx.x == 0) {  // pad odd tail so hi half is inert
        float* bp = &ldsf[(cnt >> 1) * 8];
        bp[1] = 0.f; bp[3] = 0.f; bp[5] = 0.f; bp[7] = -INFINITY;
    }
    __syncthreads();

    int base = blockIdx.x * MPB + threadIdx.x;
    v2 txx[TPT], tyy[TPT], tzz[TPT];
    float q[TPT];
#pragma unroll
    for (int k = 0; k < TPT; ++k) {
        int m = base + k * BLK;
        float x = 0.f, y = 0.f, z = 0.f;
        if (m < M) {
            x = tmpl[3 * m + 0];
            y = tmpl[3 * m + 1];
            z = tmpl[3 * m + 2];
        }
        txx[k] = (v2){x, x};
        tyy[k] = (v2){y, y};
        tzz[k] = (v2){z, z};
        q[k] = -INFINITY;
    }

    int npair = (cnt + 1) >> 1;
#pragma unroll 4
    for (int p = 0; p < npair; ++p) {
        float4 a = lds4[2 * p + 0];  // broadcast: {2x0,2x1,2y0,2y1}
        float4 b = lds4[2 * p + 1];  // {2z0,2z1,-n0,-n1}
        v2 xx = (v2){a.x, a.y};
        v2 yy = (v2){a.z, a.w};
        v2 zz = (v2){b.x, b.y};
        v2 ww = (v2){b.z, b.w};
#pragma unroll
        for (int k = 0; k < TPT; ++k) {
            v2 r = pk_fma(tzz[k], zz, ww);
            r = pk_fma(tyy[k], yy, r);
            r = pk_fma(txx[k], xx, r);
            q[k] = max3(q[k], r.x, r.y);
        }
    }

    // One relaxed fire-and-forget atomic per owned template point.
    // NO barrier / wait after these (R15 lesson).
#pragma unroll
    for (int k = 0; k < TPT; ++k) {
        int m = base + k * BLK;
        if (m < M) atomicMax(&g_qmax[m], map_f32(q[k]));
    }
}

// Final: d2 + block sums + slice re-zero + ticketed last-block final sum.
__global__ void __launch_bounds__(256) chamfer_final(
    const float* __restrict__ tmpl, float* __restrict__ blockSums,
    float* __restrict__ out, int M, int nb) {
    int bx = blockIdx.x;
    int m = bx * 256 + threadIdx.x;
    float d2 = 0.f;
    if (m < M) {
        float qmax = unmap_f32(g_qmax[m]);
        float x = tmpl[3 * m + 0];
        float y = tmpl[3 * m + 1];
        float z = tmpl[3 * m + 2];
        d2 = fmaf(x, x, fmaf(y, y, z * z)) - qmax;
        if (d2 < 0.f) d2 = 0.f;
    }
    // Re-zero own slice for the next call (this block is its sole reader;
    // stream order publishes these stores before the next main kernel).
    g_qmax[m] = 0u;  // m < 10240 < QCAP always

    for (int off = 32; off >= 1; off >>= 1) d2 += __shfl_down(d2, off, 64);
    __shared__ float wsum[4];
    __shared__ int slast;
    int lane = threadIdx.x & 63;
    int wid = threadIdx.x >> 6;
    if (lane == 0) wsum[wid] = d2;
    __syncthreads();
    if (threadIdx.x == 0) {
        blockSums[bx] = wsum[0] + wsum[1] + wsum[2] + wsum[3];
        // ACQ_REL once per block (40 total — cheap; R9's poison was
        // per-block fences at 1000x scale on the hot path).
        unsigned t = __hip_atomic_fetch_add(&g_done, 1u, __ATOMIC_ACQ_REL,
                                            __HIP_MEMORY_SCOPE_AGENT);
        int l = (t == (unsigned)(nb - 1));
        if (l)  // self-restore for the next call/replay
            __hip_atomic_store(&g_done, 0u, __ATOMIC_RELAXED,
                               __HIP_MEMORY_SCOPE_AGENT);
        slast = l;
    }
    __syncthreads();
    if (slast && threadIdx.x < 64) {
        float s = (threadIdx.x < nb)
                      ? __hip_atomic_load(&blockSums[threadIdx.x],
                                          __ATOMIC_RELAXED,
                                          __HIP_MEMORY_SCOPE_AGENT)
                      : 0.f;
        for (int off = 32; off >= 1; off >>= 1) s += __shfl_down(s, off, 64);
        if (threadIdx.x == 0) out[0] = s;
    }
}

extern "C" void kernel_launch(void* const* d_in, const int* in_sizes, int n_in,
                              void* d_out, int out_size, void* d_ws,
                              size_t ws_size, hipStream_t stream) {
    const float* scan = (const float*)d_in[0];   // [N,3]
    const float* tmpl = (const float*)d_in[1];   // [M,3]
    int N = in_sizes[0] / 3;
    int M = in_sizes[1] / 3;
    float* out = (float*)d_out;

    int GX = (M + MPB - 1) / MPB;        // 10
    int NC = (N + CHUNK - 1) / CHUNK;    // 50
    int MB = (M + 255) / 256;            // 40

    float* blockSums = (float*)d_ws;     // MB floats (written before read)

    dim3 grid(GX, NC);
    chamfer_main<<<grid, BLK, 0, stream>>>(scan, tmpl, M, N);
    chamfer_final<<<MB, 256, 0, stream>>>(tmpl, blockSums, out, M, MB);
}

// Round 17
// 25.619 us; speedup vs baseline: 2.7473x; 1.2097x over previous
//
#include <hip/hip_runtime.h>
#include <math.h>

// Directional Chamfer: sum_m min_n ||t_m - s_n||^2.
// q = 2 t.s - |s|^2 (maximize), d2 = |t|^2 - qmax.
// 2 dispatches (R15 lesson: NEVER barrier-wait in-kernel on contended
// device atomics — fire-and-forget + kernel-boundary drain is cheap):
//   1) main grid (10,200): LDS pair-packed chunk of 100 scan pts,
//      v_pk_fma_f32 + v_max3_f32, TPT=4; per-thread register max over the
//      chunk, then ONE relaxed fire-and-forget atomicMax per owned template
//      into module-scope g_qmax (order-preserving uint map -> bit-exact max).
//      2000 blocks = 8/CU = 32 waves/CU (max occupancy): R10/R11/R14/R16
//      ladder shows main is latency-bound on wave count, not atomic count.
//   2) final grid 40: one coalesced load per template, d2, fixed-order block
//      sum; each block RE-ZEROES its own g_qmax slice (sole reader; stream
//      order publishes zeros before next replay's main) -> self-restoring
//      invariant, so every call starts from g_qmax == 0 (.bss at load).
//      Last-block ticket does the fixed-order final sum -> out.
// All maxes order-independent, all sums fixed-order -> bit-deterministic.

typedef float v2 __attribute__((ext_vector_type(2)));

#define TPT 4
#define BLK 256
#define MPB (TPT * BLK)   // 1024 templates per block-stripe
#define CHUNK 100         // scan points per chunk (200*100 = 20000 exactly)
#define QCAP 16384

__device__ unsigned g_qmax[QCAP];  // .bss -> zero at module load
__device__ unsigned g_done;        // ticket; winner self-restores to 0

__device__ __forceinline__ v2 pk_fma(v2 a, v2 b, v2 c) {
    v2 d;
    asm("v_pk_fma_f32 %0, %1, %2, %3" : "=v"(d) : "v"(a), "v"(b), "v"(c));
    return d;
}
__device__ __forceinline__ float max3(float a, float b, float c) {
    float d;
    asm("v_max3_f32 %0, %1, %2, %3" : "=v"(d) : "v"(a), "v"(b), "v"(c));
    return d;
}

// Order-preserving map float -> uint32 (monotone: a<b <=> map(a)<map(b));
// map(f) > 0 for every float f, so 0 is a safe identity for max.
__device__ __forceinline__ unsigned map_f32(float f) {
    unsigned b = __float_as_uint(f);
    return (b & 0x80000000u) ? ~b : (b | 0x80000000u);
}
__device__ __forceinline__ float unmap_f32(unsigned u) {
    unsigned b = (u & 0x80000000u) ? (u ^ 0x80000000u) : ~u;
    return __uint_as_float(b);
}

__global__ void __launch_bounds__(BLK) chamfer_main(
    const float* __restrict__ scan, const float* __restrict__ tmpl, int M,
    int N) {
    __shared__ float4 lds4[CHUNK];  // 2 float4 per pair
    float* ldsf = (float*)lds4;

    int c = blockIdx.y;
    int j0 = c * CHUNK;
    int cnt = N - j0;
    if (cnt > CHUNK) cnt = CHUNK;

    for (int i = threadIdx.x; i < cnt; i += BLK) {
        float x = scan[3 * (j0 + i) + 0];
        float y = scan[3 * (j0 + i) + 1];
        float z = scan[3 * (j0 + i) + 2];
        float* bp = &ldsf[(i >> 1) * 8];
        int h = i & 1;
        bp[0 + h] = 2.f * x;
        bp[2 + h] = 2.f * y;
        bp[4 + h] = 2.f * z;
        bp[6 + h] = -(x * x + y * y + z * z);
    }
    if ((cnt & 1) && threadIdx.x == 0) {  // pad odd tail so hi half is inert
        float* bp = &ldsf[(cnt >> 1) * 8];
        bp[1] = 0.f; bp[3] = 0.f; bp[5] = 0.f; bp[7] = -INFINITY;
    }
    __syncthreads();

    int base = blockIdx.x * MPB + threadIdx.x;
    v2 txx[TPT], tyy[TPT], tzz[TPT];
    float q[TPT];
#pragma unroll
    for (int k = 0; k < TPT; ++k) {
        int m = base + k * BLK;
        float x = 0.f, y = 0.f, z = 0.f;
        if (m < M) {
            x = tmpl[3 * m + 0];
            y = tmpl[3 * m + 1];
            z = tmpl[3 * m + 2];
        }
        txx[k] = (v2){x, x};
        tyy[k] = (v2){y, y};
        tzz[k] = (v2){z, z};
        q[k] = -INFINITY;
    }

    int npair = (cnt + 1) >> 1;
#pragma unroll 4
    for (int p = 0; p < npair; ++p) {
        float4 a = lds4[2 * p + 0];  // broadcast: {2x0,2x1,2y0,2y1}
        float4 b = lds4[2 * p + 1];  // {2z0,2z1,-n0,-n1}
        v2 xx = (v2){a.x, a.y};
        v2 yy = (v2){a.z, a.w};
        v2 zz = (v2){b.x, b.y};
        v2 ww = (v2){b.z, b.w};
#pragma unroll
        for (int k = 0; k < TPT; ++k) {
            v2 r = pk_fma(tzz[k], zz, ww);
            r = pk_fma(tyy[k], yy, r);
            r = pk_fma(txx[k], xx, r);
            q[k] = max3(q[k], r.x, r.y);
        }
    }

    // One relaxed fire-and-forget atomic per owned template point.
    // NO barrier / wait after these (R15 lesson).
#pragma unroll
    for (int k = 0; k < TPT; ++k) {
        int m = base + k * BLK;
        if (m < M) atomicMax(&g_qmax[m], map_f32(q[k]));
    }
}

// Final: d2 + block sums + slice re-zero + ticketed last-block final sum.
__global__ void __launch_bounds__(256) chamfer_final(
    const float* __restrict__ tmpl, float* __restrict__ blockSums,
    float* __restrict__ out, int M, int nb) {
    int bx = blockIdx.x;
    int m = bx * 256 + threadIdx.x;
    float d2 = 0.f;
    if (m < M) {
        float qmax = unmap_f32(g_qmax[m]);
        float x = tmpl[3 * m + 0];
        float y = tmpl[3 * m + 1];
        float z = tmpl[3 * m + 2];
        d2 = fmaf(x, x, fmaf(y, y, z * z)) - qmax;
        if (d2 < 0.f) d2 = 0.f;
    }
    // Re-zero own slice for the next call (this block is its sole reader;
    // stream order publishes these stores before the next main kernel).
    g_qmax[m] = 0u;  // m < 10240 < QCAP always

    for (int off = 32; off >= 1; off >>= 1) d2 += __shfl_down(d2, off, 64);
    __shared__ float wsum[4];
    __shared__ int slast;
    int lane = threadIdx.x & 63;
    int wid = threadIdx.x >> 6;
    if (lane == 0) wsum[wid] = d2;
    __syncthreads();
    if (threadIdx.x == 0) {
        blockSums[bx] = wsum[0] + wsum[1] + wsum[2] + wsum[3];
        unsigned t = __hip_atomic_fetch_add(&g_done, 1u, __ATOMIC_ACQ_REL,
                                            __HIP_MEMORY_SCOPE_AGENT);
        int l = (t == (unsigned)(nb - 1));
        if (l)  // self-restore for the next call/replay
            __hip_atomic_store(&g_done, 0u, __ATOMIC_RELAXED,
                               __HIP_MEMORY_SCOPE_AGENT);
        slast = l;
    }
    __syncthreads();
    if (slast && threadIdx.x < 64) {
        float s = (threadIdx.x < nb)
                      ? __hip_atomic_load(&blockSums[threadIdx.x],
                                          __ATOMIC_RELAXED,
                                          __HIP_MEMORY_SCOPE_AGENT)
                      : 0.f;
        for (int off = 32; off >= 1; off >>= 1) s += __shfl_down(s, off, 64);
        if (threadIdx.x == 0) out[0] = s;
    }
}

extern "C" void kernel_launch(void* const* d_in, const int* in_sizes, int n_in,
                              void* d_out, int out_size, void* d_ws,
                              size_t ws_size, hipStream_t stream) {
    const float* scan = (const float*)d_in[0];   // [N,3]
    const float* tmpl = (const float*)d_in[1];   // [M,3]
    int N = in_sizes[0] / 3;
    int M = in_sizes[1] / 3;
    float* out = (float*)d_out;

    int GX = (M + MPB - 1) / MPB;        // 10
    int NC = (N + CHUNK - 1) / CHUNK;    // 200
    int MB = (M + 255) / 256;            // 40

    float* blockSums = (float*)d_ws;     // MB floats (written before read)

    dim3 grid(GX, NC);
    chamfer_main<<<grid, BLK, 0, stream>>>(scan, tmpl, M, N);
    chamfer_final<<<MB, 256, 0, stream>>>(tmpl, blockSums, out, M, MB);
}